// Round 8
// baseline (392.193 us; speedup 1.0000x reference)
//
#include <hip/hip_runtime.h>
#include <cstdint>
#include <cstddef>

// ---------------------------------------------------------------------------
// FastQuantumEvolution, dim-sliced L2-resident CSR gather.
//   dis = rsqrt(deg_col + 1)
//   prop(h)[r] = dis[r] * ( Sum_{e: row=r} h[c]*dis[c] + h[r]*dis[r] )
//   fo = prop(x); evolved = x + i*c1*fo - (c1^2/2)*prop(fo),  c1 = t*s
//   w[n] = sum_d |evolved|^2 ; w *= N / sum(w)
// CSR build with ZERO global atomics (R7's k_hist was far-atomic-bound:
// 3.2M device atomics x 32B fabric = 106 MB WRITE_SIZE, 146 us):
// LDS-privatized histograms over node ranges + per-slice offsets + LDS
// cursors for the scatter. D=32 split into 4 slices of 8 dims for the
// gather passes (per-slice operand 3.2 MB < 4 MB per-XCD L2).
// Output: [ w (N floats) | evolved (real-only N*32 OR interleaved N*64) ]
// ---------------------------------------------------------------------------

#define TPB 256
#define BSL 32          // edge slices
#define CRANGE 32768    // count range: packed u16 pairs -> 64KB LDS
#define SRANGE 16384    // scatter range: int cursors   -> 64KB LDS

__device__ __forceinline__ uint32_t f2bf(float f) {
    uint32_t u = __float_as_uint(f);
    return (u + 0x7FFFu + ((u >> 16) & 1u)) >> 16;  // RNE
}
__device__ __forceinline__ uint32_t pack2(float re, float im) {
    return f2bf(re) | (f2bf(im) << 16);
}
__device__ __forceinline__ float bflo(uint32_t p) { return __uint_as_float(p << 16); }
__device__ __forceinline__ float bfhi(uint32_t p) { return __uint_as_float(p & 0xFFFF0000u); }

// Per-(range, slice) LDS histogram of keys; packed u16-pair counts.
__global__ void k_cnt(const int* __restrict__ keys, int E, int Nw,
                      uint32_t* __restrict__ parts) {
    __shared__ uint32_t sh[CRANGE / 2];
    int r = blockIdx.x / BSL, b = blockIdx.x % BSL;
    int rbase = r * CRANGE;
    for (int i = threadIdx.x; i < CRANGE / 2; i += TPB) sh[i] = 0;
    __syncthreads();
    int SL = (E + BSL - 1) / BSL;
    int s0 = b * SL, s1 = min(E, s0 + SL);
    for (int e = s0 + threadIdx.x; e < s1; e += TPB) {
        int k = keys[e] - rbase;
        if ((unsigned)k < CRANGE)
            atomicAdd(&sh[k >> 1], 1u << ((k & 1) * 16));
    }
    __syncthreads();
    int wbase = rbase >> 1;
    for (int i = threadIdx.x; i < CRANGE / 2; i += TPB) {
        int w = wbase + i;
        if (w < Nw) parts[(size_t)b * Nw + w] = sh[i];
    }
}

// dis[n] = rsqrt(col-degree + 1) from packed partials.
__global__ void k_discol(const uint32_t* __restrict__ parts, int Nw, int N,
                         float* __restrict__ dis) {
    int w = blockIdx.x * blockDim.x + threadIdx.x;
    if (w >= Nw) return;
    uint32_t lo = 0, hi = 0;
    for (int b = 0; b < BSL; ++b) {
        uint32_t v = parts[(size_t)b * Nw + w];
        lo += v & 0xFFFFu; hi += v >> 16;
    }
    int n = 2 * w;
    if (n < N)     dis[n]     = rsqrtf((float)lo + 1.0f);
    if (n + 1 < N) dis[n + 1] = rsqrtf((float)hi + 1.0f);
}

// Per-row: exclusive scan across slices -> sliceoff (u8), total -> rowcnt.
__global__ void k_redrow(const uint32_t* __restrict__ parts, int Nw, int N,
                         unsigned char* __restrict__ sliceoff,
                         int* __restrict__ rowcnt) {
    int w = blockIdx.x * blockDim.x + threadIdx.x;
    if (w >= Nw) return;
    uint32_t lo = 0, hi = 0;
    int n = 2 * w;
    for (int b = 0; b < BSL; ++b) {
        uint32_t v = parts[(size_t)b * Nw + w];
        if (n < N)     sliceoff[(size_t)b * N + n]     = (unsigned char)lo;
        if (n + 1 < N) sliceoff[(size_t)b * N + n + 1] = (unsigned char)hi;
        lo += v & 0xFFFFu; hi += v >> 16;
    }
    if (n < N)     rowcnt[n]     = (int)lo;
    if (n + 1 < N) rowcnt[n + 1] = (int)hi;
}

// exclusive scan, 1024 elems per 256-thread block
__global__ void k_scan1(const int* __restrict__ in, int* __restrict__ out,
                        int* __restrict__ partials, int N) {
    __shared__ int sh[256];
    int t = threadIdx.x;
    int base = blockIdx.x * 1024 + t * 4;
    int v0 = (base + 0 < N) ? in[base + 0] : 0;
    int v1 = (base + 1 < N) ? in[base + 1] : 0;
    int v2 = (base + 2 < N) ? in[base + 2] : 0;
    int v3 = (base + 3 < N) ? in[base + 3] : 0;
    int s = v0 + v1 + v2 + v3;
    sh[t] = s;
    __syncthreads();
    for (int off = 1; off < 256; off <<= 1) {
        int add = (t >= off) ? sh[t - off] : 0;
        __syncthreads();
        sh[t] += add;
        __syncthreads();
    }
    int excl = sh[t] - s;
    if (base + 0 < N) out[base + 0] = excl;
    excl += v0;
    if (base + 1 < N) out[base + 1] = excl;
    excl += v1;
    if (base + 2 < N) out[base + 2] = excl;
    excl += v2;
    if (base + 3 < N) out[base + 3] = excl;
    if (t == 255) partials[blockIdx.x] = sh[255];
}

__global__ void k_scan2(int* __restrict__ partials, int nb) {
    if (threadIdx.x == 0 && blockIdx.x == 0) {
        int acc = 0;
        for (int i = 0; i < nb; ++i) { int v = partials[i]; partials[i] = acc; acc += v; }
    }
}

__global__ void k_scan3(int* __restrict__ out, const int* __restrict__ partials,
                        int N, int E) {
    int i = blockIdx.x * blockDim.x + threadIdx.x;
    if (i < N) out[i] += partials[i >> 10];
    if (i == 0) out[N] = E;
}

// Scatter with LDS cursors initialized to rowptr + sliceoff; one LDS atomic
// per edge, plain global store. Zero global atomics.
__global__ void k_scatter2(const int* __restrict__ row, const int* __restrict__ col,
                           int E, int N, const int* __restrict__ rowptr,
                           const unsigned char* __restrict__ sliceoff,
                           int* __restrict__ ecol) {
    __shared__ int cur[SRANGE];
    int r = blockIdx.x / BSL, b = blockIdx.x % BSL;
    int rbase = r * SRANGE;
    for (int i = threadIdx.x; i < SRANGE; i += TPB) {
        int n = rbase + i;
        cur[i] = (n < N) ? rowptr[n] + (int)sliceoff[(size_t)b * N + n] : 0;
    }
    __syncthreads();
    int SL = (E + BSL - 1) / BSL;
    int s0 = b * SL, s1 = min(E, s0 + SL);
    for (int e = s0 + threadIdx.x; e < s1; e += TPB) {
        int rv = row[e] - rbase;
        int cv = col[e];
        if ((unsigned)rv < SRANGE) {
            int pos = atomicAdd(&cur[rv], 1);
            ecol[pos] = cv;
        }
    }
}

// xds[s][n][dd] = pack2(x*dis) for dim k = 8s+dd  (sliced, premultiplied)
__global__ void k_pack(const float* __restrict__ xr, const float* __restrict__ xi,
                       const float* __restrict__ dis, uint32_t* __restrict__ xds,
                       int N) {
    int i = blockIdx.x * blockDim.x + threadIdx.x;
    if (i < N * 32) {
        int n = i >> 5, k = i & 31, s = k >> 3, dd = k & 7;
        float dg = dis[n];
        xds[((size_t)s * N + n) * 8 + dd] = pack2(xr[i] * dg, xi[i] * dg);
    }
}

// Gather-accumulate over one node's edges from an 8-dim slice operand.
// 8-lane group per node; lane dd owns dim dd. 16 gathers in flight.
__device__ __forceinline__ void edge_accum8(const int* __restrict__ ecol,
                                            const uint32_t* __restrict__ hb,
                                            int beg, int end, int dd,
                                            float& aR, float& aI) {
    for (int base = beg; base < end; base += 16) {
        int m = end - base;
        int c0 = (dd < m)     ? ecol[base + dd]     : -1;
        int c1 = (8 + dd < m) ? ecol[base + 8 + dd] : -1;
        int cc[16];
        uint32_t p[16];
        #pragma unroll
        for (int k = 0; k < 8; ++k) {
            cc[k]     = __shfl(c0, k, 8);
            cc[k + 8] = __shfl(c1, k, 8);
        }
        #pragma unroll
        for (int k = 0; k < 16; ++k) {
            int c = cc[k] < 0 ? 0 : cc[k];
            p[k] = hb[c * 8 + dd];
        }
        #pragma unroll
        for (int k = 0; k < 16; ++k)
            if (cc[k] >= 0) { aR += bflo(p[k]); aI += bfhi(p[k]); }
    }
}

// Pass 1: fo = dis*(sum + self). Writes fo2b (bf16 fo) + fods (bf16 fo*dis).
__global__ void k_p1(const int* __restrict__ rowptr, const int* __restrict__ ecol,
                     const float* __restrict__ dis, const uint32_t* __restrict__ xds,
                     uint32_t* __restrict__ fo2b, uint32_t* __restrict__ fods, int N) {
    int s  = blockIdx.x & 3;
    int nb = blockIdx.x >> 2;
    int r  = nb * 32 + (threadIdx.x >> 3);
    int dd = threadIdx.x & 7;
    if (r >= N) return;
    const uint32_t* hb = xds + (size_t)s * N * 8;
    int beg = rowptr[r], end = rowptr[r + 1];
    float dg = dis[r];
    float aR = 0.f, aI = 0.f;
    edge_accum8(ecol, hb, beg, end, dd, aR, aI);
    uint32_t sv = hb[r * 8 + dd];  // self loop: x[r]*dis[r] (premultiplied)
    aR += bflo(sv); aI += bfhi(sv);
    float foR = dg * aR, foI = dg * aI;
    size_t o = (size_t)s * N * 8 + (size_t)r * 8 + dd;
    fo2b[o] = pack2(foR, foI);
    fods[o] = pack2(foR * dg, foI * dg);  // premultiplied for pass 2
}

// Pass 2: so = dis*(sum + self); delta = (-c1*foI - c2h*soR, c1*foR - c2h*soI).
__global__ void k_p2(const int* __restrict__ rowptr, const int* __restrict__ ecol,
                     const float* __restrict__ dis, const uint32_t* __restrict__ fo2b,
                     const uint32_t* __restrict__ fods,
                     const float* __restrict__ tptr, const float* __restrict__ dptr,
                     uint32_t* __restrict__ delta, int N) {
    int s  = blockIdx.x & 3;
    int nb = blockIdx.x >> 2;
    int r  = nb * 32 + (threadIdx.x >> 3);
    int dd = threadIdx.x & 7;
    if (r >= N) return;
    const uint32_t* hb = fods + (size_t)s * N * 8;
    int beg = rowptr[r], end = rowptr[r + 1];
    float dg = dis[r];
    float aR = 0.f, aI = 0.f;
    edge_accum8(ecol, hb, beg, end, dd, aR, aI);
    uint32_t sv = hb[r * 8 + dd];  // self loop: fo[r]*dis[r]
    aR += bflo(sv); aI += bfhi(sv);
    float soR = dg * aR, soI = dg * aI;
    size_t o = (size_t)s * N * 8 + (size_t)r * 8 + dd;
    uint32_t fp = fo2b[o];
    float foR = bflo(fp), foI = bfhi(fp);
    float c1  = tptr[0] * dptr[0];
    float c2h = 0.5f * c1 * c1;
    delta[o] = pack2(-c1 * foI - c2h * soR, c1 * foR - c2h * soI);
}

// Final: evolved = x + delta (exact f32 base), per-node w, per-BLOCK partial
// (plain store). One thread = (node n, slice s) = 8 dims.
__global__ void k_final(const float* __restrict__ xr, const float* __restrict__ xi,
                        const uint32_t* __restrict__ delta, float* __restrict__ out,
                        int N, int interleaved, float* __restrict__ partials2) {
    int t = blockIdx.x * blockDim.x + threadIdx.x;
    int n = t >> 2, s = t & 3;
    float wsum = 0.f;
    if (n < N) {
        const uint4* dp = (const uint4*)(delta + ((size_t)s * N + n) * 8);
        uint4 d0 = dp[0], d1 = dp[1];
        size_t ib = (size_t)n * 32 + (size_t)s * 8;
        const float4* xr4 = (const float4*)(xr + ib);
        const float4* xi4 = (const float4*)(xi + ib);
        float4 a0 = xr4[0], a1 = xr4[1];
        float4 b0 = xi4[0], b1 = xi4[1];
        uint32_t dv[8] = {d0.x, d0.y, d0.z, d0.w, d1.x, d1.y, d1.z, d1.w};
        float ar[8] = {a0.x, a0.y, a0.z, a0.w, a1.x, a1.y, a1.z, a1.w};
        float ai[8] = {b0.x, b0.y, b0.z, b0.w, b1.x, b1.y, b1.z, b1.w};
        float er[8], ei[8];
        #pragma unroll
        for (int k = 0; k < 8; ++k) {
            er[k] = ar[k] + bflo(dv[k]);
            ei[k] = ai[k] + bfhi(dv[k]);
            wsum += er[k] * er[k] + ei[k] * ei[k];
        }
        if (interleaved) {
            float4* op = (float4*)(out + N + 2 * ib);
            op[0] = make_float4(er[0], ei[0], er[1], ei[1]);
            op[1] = make_float4(er[2], ei[2], er[3], ei[3]);
            op[2] = make_float4(er[4], ei[4], er[5], ei[5]);
            op[3] = make_float4(er[6], ei[6], er[7], ei[7]);
        } else {
            float4* op = (float4*)(out + N + ib);
            op[0] = make_float4(er[0], er[1], er[2], er[3]);
            op[1] = make_float4(er[4], er[5], er[6], er[7]);
        }
    }
    float nodesum = wsum;
    nodesum += __shfl_xor(nodesum, 1, 4);
    nodesum += __shfl_xor(nodesum, 2, 4);
    if (n < N && s == 0) out[n] = nodesum;  // unnormalized w
    float bv = wsum;
    #pragma unroll
    for (int off = 32; off; off >>= 1) bv += __shfl_xor(bv, off, 64);
    __shared__ float ls[TPB / 64];
    if ((threadIdx.x & 63) == 0) ls[threadIdx.x >> 6] = bv;
    __syncthreads();
    if (threadIdx.x == 0) {
        float bs = 0.f;
        #pragma unroll
        for (int i = 0; i < TPB / 64; ++i) bs += ls[i];
        partials2[blockIdx.x] = bs;
    }
}

__global__ void k_sum(const float* __restrict__ partials2, int nb,
                      float* __restrict__ S) {
    float acc = 0.f;
    for (int i = threadIdx.x; i < nb; i += blockDim.x) acc += partials2[i];
    #pragma unroll
    for (int off = 32; off; off >>= 1) acc += __shfl_xor(acc, off, 64);
    __shared__ float ls[TPB / 64];
    if ((threadIdx.x & 63) == 0) ls[threadIdx.x >> 6] = acc;
    __syncthreads();
    if (threadIdx.x == 0) {
        float s = 0.f;
        #pragma unroll
        for (int i = 0; i < TPB / 64; ++i) s += ls[i];
        *S = s;
    }
}

__global__ void k_norm(float* __restrict__ w, int N, const float* __restrict__ S) {
    int i = blockIdx.x * blockDim.x + threadIdx.x;
    if (i >= N) return;
    float s = *S;
    w[i] = (s > 1e-8f) ? w[i] * ((float)N / s) : 1.0f;
}

extern "C" void kernel_launch(void* const* d_in, const int* in_sizes, int n_in,
                              void* d_out, int out_size, void* d_ws, size_t ws_size,
                              hipStream_t stream) {
    const float* xr   = (const float*)d_in[0];
    const float* xi   = (const float*)d_in[1];
    const int*   eidx = (const int*)d_in[2];
    const float* tptr = (const float*)d_in[3];
    const float* dptr = (const float*)d_in[4];

    const int N = in_sizes[0] / 32;
    const int E = in_sizes[2] / 2;
    const int* row = eidx;
    const int* col = eidx + E;
    const long long ND = (long long)N * 32;
    const int Nw  = (N + 1) / 2;
    const int NB  = (N + 1023) / 1024;                 // scan blocks
    const int NBK = (N + 31) / 32;                     // node blocks (gather)
    const int NFB = (int)((ND / 8 + TPB - 1) / TPB);   // k_final blocks
    const int NCR = (N + CRANGE - 1) / CRANGE;
    const int NSR = (N + SRANGE - 1) / SRANGE;

    // ws allocation in 4B words, 4-word aligned chunks
    size_t o = 0;
    auto alloc = [&](size_t words) {
        o = (o + 3) & ~(size_t)3;
        size_t r = o; o += words; return r;
    };
    uint32_t* wsw = (uint32_t*)d_ws;
    uint32_t*      parts_row = wsw + alloc((size_t)BSL * Nw);
    uint32_t*      parts_col = wsw + alloc((size_t)BSL * Nw);
    unsigned char* sliceoff  = (unsigned char*)(wsw + alloc(((size_t)BSL * N + 3) / 4));
    int*           rowcnt    = (int*)(wsw + alloc(N));
    int*           rowptr    = (int*)(wsw + alloc(N + 1));
    int*           partials  = (int*)(wsw + alloc(NB));
    float*         dis       = (float*)(wsw + alloc(N));
    uint32_t*      xds       = wsw + alloc(ND);
    uint32_t*      fo2b      = wsw + alloc(ND);
    uint32_t*      fods      = wsw + alloc(ND);
    uint32_t*      delta     = wsw + alloc(ND);
    int*           ecol      = (int*)(wsw + alloc(E));
    float*         partials2 = (float*)(wsw + alloc(NFB));
    float*         S         = (float*)(wsw + alloc(1));

    int interleaved = (out_size >= (int)(N + 2 * ND)) ? 1 : 0;
    float* out = (float*)d_out;

    // --- CSR build (no global atomics) ---
    k_cnt<<<NCR * BSL, TPB, 0, stream>>>(col, E, Nw, parts_col);
    k_cnt<<<NCR * BSL, TPB, 0, stream>>>(row, E, Nw, parts_row);
    k_discol<<<(Nw + TPB - 1) / TPB, TPB, 0, stream>>>(parts_col, Nw, N, dis);
    k_redrow<<<(Nw + TPB - 1) / TPB, TPB, 0, stream>>>(parts_row, Nw, N,
                                                       sliceoff, rowcnt);
    k_scan1<<<NB, TPB, 0, stream>>>(rowcnt, rowptr, partials, N);
    k_scan2<<<1, 64, 0, stream>>>(partials, NB);
    k_scan3<<<(N + TPB - 1) / TPB, TPB, 0, stream>>>(rowptr, partials, N, E);
    k_scatter2<<<NSR * BSL, TPB, 0, stream>>>(row, col, E, N, rowptr,
                                              sliceoff, ecol);

    // --- evolution ---
    k_pack<<<(int)((ND + TPB - 1) / TPB), TPB, 0, stream>>>(xr, xi, dis, xds, N);
    int pgrid = 4 * NBK;  // slice = blockIdx.x & 3
    k_p1<<<pgrid, TPB, 0, stream>>>(rowptr, ecol, dis, xds, fo2b, fods, N);
    k_p2<<<pgrid, TPB, 0, stream>>>(rowptr, ecol, dis, fo2b, fods, tptr, dptr,
                                    delta, N);
    k_final<<<NFB, TPB, 0, stream>>>(xr, xi, delta, out, N, interleaved, partials2);
    k_sum<<<1, TPB, 0, stream>>>(partials2, NFB, S);
    k_norm<<<(N + TPB - 1) / TPB, TPB, 0, stream>>>(out, N, S);
}

// Round 9
// 365.980 us; speedup vs baseline: 1.0716x; 1.0716x over previous
//
#include <hip/hip_runtime.h>
#include <cstdint>
#include <cstddef>

// ---------------------------------------------------------------------------
// FastQuantumEvolution, dim-sliced L2-resident CSR gather.
//   dis = rsqrt(deg_col + 1)
//   prop(h)[r] = dis[r] * ( Sum_{e: row=r} h[c]*dis[c] + h[r]*dis[r] )
//   fo = prop(x); evolved = x + i*c1*fo - (c1^2/2)*prop(fo),  c1 = t*s
//   w[n] = sum_d |evolved|^2 ; w *= N / sum(w)
// CSR build with ZERO global atomics. R8 lesson: 64KB-LDS blocks -> 2/CU,
// 8% occupancy, latency-bound (116us scatter). R9: 32KB LDS tiles
// (CRANGE 16384, SRANGE 8192) -> 5 blocks/CU, 416-block scatter grid.
// D=32 split into 4 slices of 8 dims for the gather passes (per-slice
// operand 3.2 MB < 4 MB per-XCD L2).
// Output: [ w (N floats) | evolved (real-only N*32 OR interleaved N*64) ]
// ---------------------------------------------------------------------------

#define TPB 256
#define BSL 32          // edge slices
#define CRANGE 16384    // count range: packed u16 pairs -> 32KB LDS
#define SRANGE 8192     // scatter range: int cursors    -> 32KB LDS

__device__ __forceinline__ uint32_t f2bf(float f) {
    uint32_t u = __float_as_uint(f);
    return (u + 0x7FFFu + ((u >> 16) & 1u)) >> 16;  // RNE
}
__device__ __forceinline__ uint32_t pack2(float re, float im) {
    return f2bf(re) | (f2bf(im) << 16);
}
__device__ __forceinline__ float bflo(uint32_t p) { return __uint_as_float(p << 16); }
__device__ __forceinline__ float bfhi(uint32_t p) { return __uint_as_float(p & 0xFFFF0000u); }

// Per-(range, slice) LDS histogram of keys; packed u16-pair counts.
__global__ void k_cnt(const int* __restrict__ keys, int E, int Nw,
                      uint32_t* __restrict__ parts) {
    __shared__ uint32_t sh[CRANGE / 2];
    int r = blockIdx.x / BSL, b = blockIdx.x % BSL;
    int rbase = r * CRANGE;
    for (int i = threadIdx.x; i < CRANGE / 2; i += TPB) sh[i] = 0;
    __syncthreads();
    int SL = (E + BSL - 1) / BSL;
    int s0 = b * SL, s1 = min(E, s0 + SL);
    for (int e = s0 + threadIdx.x; e < s1; e += TPB) {
        int k = keys[e] - rbase;
        if ((unsigned)k < CRANGE)
            atomicAdd(&sh[k >> 1], 1u << ((k & 1) * 16));
    }
    __syncthreads();
    int wbase = rbase >> 1;
    for (int i = threadIdx.x; i < CRANGE / 2; i += TPB) {
        int w = wbase + i;
        if (w < Nw) parts[(size_t)b * Nw + w] = sh[i];
    }
}

// dis[n] = rsqrt(col-degree + 1) from packed partials.
__global__ void k_discol(const uint32_t* __restrict__ parts, int Nw, int N,
                         float* __restrict__ dis) {
    int w = blockIdx.x * blockDim.x + threadIdx.x;
    if (w >= Nw) return;
    uint32_t lo = 0, hi = 0;
    for (int b = 0; b < BSL; ++b) {
        uint32_t v = parts[(size_t)b * Nw + w];
        lo += v & 0xFFFFu; hi += v >> 16;
    }
    int n = 2 * w;
    if (n < N)     dis[n]     = rsqrtf((float)lo + 1.0f);
    if (n + 1 < N) dis[n + 1] = rsqrtf((float)hi + 1.0f);
}

// Per-row: exclusive scan across slices -> sliceoff (u8), total -> rowcnt.
__global__ void k_redrow(const uint32_t* __restrict__ parts, int Nw, int N,
                         unsigned char* __restrict__ sliceoff,
                         int* __restrict__ rowcnt) {
    int w = blockIdx.x * blockDim.x + threadIdx.x;
    if (w >= Nw) return;
    uint32_t lo = 0, hi = 0;
    int n = 2 * w;
    for (int b = 0; b < BSL; ++b) {
        uint32_t v = parts[(size_t)b * Nw + w];
        if (n < N)     sliceoff[(size_t)b * N + n]     = (unsigned char)lo;
        if (n + 1 < N) sliceoff[(size_t)b * N + n + 1] = (unsigned char)hi;
        lo += v & 0xFFFFu; hi += v >> 16;
    }
    if (n < N)     rowcnt[n]     = (int)lo;
    if (n + 1 < N) rowcnt[n + 1] = (int)hi;
}

// exclusive scan, 1024 elems per 256-thread block
__global__ void k_scan1(const int* __restrict__ in, int* __restrict__ out,
                        int* __restrict__ partials, int N) {
    __shared__ int sh[256];
    int t = threadIdx.x;
    int base = blockIdx.x * 1024 + t * 4;
    int v0 = (base + 0 < N) ? in[base + 0] : 0;
    int v1 = (base + 1 < N) ? in[base + 1] : 0;
    int v2 = (base + 2 < N) ? in[base + 2] : 0;
    int v3 = (base + 3 < N) ? in[base + 3] : 0;
    int s = v0 + v1 + v2 + v3;
    sh[t] = s;
    __syncthreads();
    for (int off = 1; off < 256; off <<= 1) {
        int add = (t >= off) ? sh[t - off] : 0;
        __syncthreads();
        sh[t] += add;
        __syncthreads();
    }
    int excl = sh[t] - s;
    if (base + 0 < N) out[base + 0] = excl;
    excl += v0;
    if (base + 1 < N) out[base + 1] = excl;
    excl += v1;
    if (base + 2 < N) out[base + 2] = excl;
    excl += v2;
    if (base + 3 < N) out[base + 3] = excl;
    if (t == 255) partials[blockIdx.x] = sh[255];
}

__global__ void k_scan2(int* __restrict__ partials, int nb) {
    if (threadIdx.x == 0 && blockIdx.x == 0) {
        int acc = 0;
        for (int i = 0; i < nb; ++i) { int v = partials[i]; partials[i] = acc; acc += v; }
    }
}

__global__ void k_scan3(int* __restrict__ out, const int* __restrict__ partials,
                        int N, int E) {
    int i = blockIdx.x * blockDim.x + threadIdx.x;
    if (i < N) out[i] += partials[i >> 10];
    if (i == 0) out[N] = E;
}

// Scatter with LDS cursors initialized to rowptr + sliceoff; one LDS atomic
// per edge, plain global store. Zero global atomics.
__global__ void k_scatter2(const int* __restrict__ row, const int* __restrict__ col,
                           int E, int N, const int* __restrict__ rowptr,
                           const unsigned char* __restrict__ sliceoff,
                           int* __restrict__ ecol) {
    __shared__ int cur[SRANGE];
    int r = blockIdx.x / BSL, b = blockIdx.x % BSL;
    int rbase = r * SRANGE;
    for (int i = threadIdx.x; i < SRANGE; i += TPB) {
        int n = rbase + i;
        cur[i] = (n < N) ? rowptr[n] + (int)sliceoff[(size_t)b * N + n] : 0;
    }
    __syncthreads();
    int SL = (E + BSL - 1) / BSL;
    int s0 = b * SL, s1 = min(E, s0 + SL);
    for (int e = s0 + threadIdx.x; e < s1; e += TPB) {
        int rv = row[e] - rbase;
        int cv = col[e];
        if ((unsigned)rv < SRANGE) {
            int pos = atomicAdd(&cur[rv], 1);
            ecol[pos] = cv;
        }
    }
}

// xds[s][n][dd] = pack2(x*dis) for dim k = 8s+dd  (sliced, premultiplied)
__global__ void k_pack(const float* __restrict__ xr, const float* __restrict__ xi,
                       const float* __restrict__ dis, uint32_t* __restrict__ xds,
                       int N) {
    int i = blockIdx.x * blockDim.x + threadIdx.x;
    if (i < N * 32) {
        int n = i >> 5, k = i & 31, s = k >> 3, dd = k & 7;
        float dg = dis[n];
        xds[((size_t)s * N + n) * 8 + dd] = pack2(xr[i] * dg, xi[i] * dg);
    }
}

// Gather-accumulate over one node's edges from an 8-dim slice operand.
// 8-lane group per node; lane dd owns dim dd. 16 gathers in flight.
__device__ __forceinline__ void edge_accum8(const int* __restrict__ ecol,
                                            const uint32_t* __restrict__ hb,
                                            int beg, int end, int dd,
                                            float& aR, float& aI) {
    for (int base = beg; base < end; base += 16) {
        int m = end - base;
        int c0 = (dd < m)     ? ecol[base + dd]     : -1;
        int c1 = (8 + dd < m) ? ecol[base + 8 + dd] : -1;
        int cc[16];
        uint32_t p[16];
        #pragma unroll
        for (int k = 0; k < 8; ++k) {
            cc[k]     = __shfl(c0, k, 8);
            cc[k + 8] = __shfl(c1, k, 8);
        }
        #pragma unroll
        for (int k = 0; k < 16; ++k) {
            int c = cc[k] < 0 ? 0 : cc[k];
            p[k] = hb[c * 8 + dd];
        }
        #pragma unroll
        for (int k = 0; k < 16; ++k)
            if (cc[k] >= 0) { aR += bflo(p[k]); aI += bfhi(p[k]); }
    }
}

// Pass 1: fo = dis*(sum + self). Writes fo2b (bf16 fo) + fods (bf16 fo*dis).
__global__ void k_p1(const int* __restrict__ rowptr, const int* __restrict__ ecol,
                     const float* __restrict__ dis, const uint32_t* __restrict__ xds,
                     uint32_t* __restrict__ fo2b, uint32_t* __restrict__ fods, int N) {
    int s  = blockIdx.x & 3;
    int nb = blockIdx.x >> 2;
    int r  = nb * 32 + (threadIdx.x >> 3);
    int dd = threadIdx.x & 7;
    if (r >= N) return;
    const uint32_t* hb = xds + (size_t)s * N * 8;
    int beg = rowptr[r], end = rowptr[r + 1];
    float dg = dis[r];
    float aR = 0.f, aI = 0.f;
    edge_accum8(ecol, hb, beg, end, dd, aR, aI);
    uint32_t sv = hb[r * 8 + dd];  // self loop: x[r]*dis[r] (premultiplied)
    aR += bflo(sv); aI += bfhi(sv);
    float foR = dg * aR, foI = dg * aI;
    size_t o = (size_t)s * N * 8 + (size_t)r * 8 + dd;
    fo2b[o] = pack2(foR, foI);
    fods[o] = pack2(foR * dg, foI * dg);  // premultiplied for pass 2
}

// Pass 2: so = dis*(sum + self); delta = (-c1*foI - c2h*soR, c1*foR - c2h*soI).
__global__ void k_p2(const int* __restrict__ rowptr, const int* __restrict__ ecol,
                     const float* __restrict__ dis, const uint32_t* __restrict__ fo2b,
                     const uint32_t* __restrict__ fods,
                     const float* __restrict__ tptr, const float* __restrict__ dptr,
                     uint32_t* __restrict__ delta, int N) {
    int s  = blockIdx.x & 3;
    int nb = blockIdx.x >> 2;
    int r  = nb * 32 + (threadIdx.x >> 3);
    int dd = threadIdx.x & 7;
    if (r >= N) return;
    const uint32_t* hb = fods + (size_t)s * N * 8;
    int beg = rowptr[r], end = rowptr[r + 1];
    float dg = dis[r];
    float aR = 0.f, aI = 0.f;
    edge_accum8(ecol, hb, beg, end, dd, aR, aI);
    uint32_t sv = hb[r * 8 + dd];  // self loop: fo[r]*dis[r]
    aR += bflo(sv); aI += bfhi(sv);
    float soR = dg * aR, soI = dg * aI;
    size_t o = (size_t)s * N * 8 + (size_t)r * 8 + dd;
    uint32_t fp = fo2b[o];
    float foR = bflo(fp), foI = bfhi(fp);
    float c1  = tptr[0] * dptr[0];
    float c2h = 0.5f * c1 * c1;
    delta[o] = pack2(-c1 * foI - c2h * soR, c1 * foR - c2h * soI);
}

// Final: evolved = x + delta (exact f32 base), per-node w, per-BLOCK partial
// (plain store). One thread = (node n, slice s) = 8 dims.
__global__ void k_final(const float* __restrict__ xr, const float* __restrict__ xi,
                        const uint32_t* __restrict__ delta, float* __restrict__ out,
                        int N, int interleaved, float* __restrict__ partials2) {
    int t = blockIdx.x * blockDim.x + threadIdx.x;
    int n = t >> 2, s = t & 3;
    float wsum = 0.f;
    if (n < N) {
        const uint4* dp = (const uint4*)(delta + ((size_t)s * N + n) * 8);
        uint4 d0 = dp[0], d1 = dp[1];
        size_t ib = (size_t)n * 32 + (size_t)s * 8;
        const float4* xr4 = (const float4*)(xr + ib);
        const float4* xi4 = (const float4*)(xi + ib);
        float4 a0 = xr4[0], a1 = xr4[1];
        float4 b0 = xi4[0], b1 = xi4[1];
        uint32_t dv[8] = {d0.x, d0.y, d0.z, d0.w, d1.x, d1.y, d1.z, d1.w};
        float ar[8] = {a0.x, a0.y, a0.z, a0.w, a1.x, a1.y, a1.z, a1.w};
        float ai[8] = {b0.x, b0.y, b0.z, b0.w, b1.x, b1.y, b1.z, b1.w};
        float er[8], ei[8];
        #pragma unroll
        for (int k = 0; k < 8; ++k) {
            er[k] = ar[k] + bflo(dv[k]);
            ei[k] = ai[k] + bfhi(dv[k]);
            wsum += er[k] * er[k] + ei[k] * ei[k];
        }
        if (interleaved) {
            float4* op = (float4*)(out + N + 2 * ib);
            op[0] = make_float4(er[0], ei[0], er[1], ei[1]);
            op[1] = make_float4(er[2], ei[2], er[3], ei[3]);
            op[2] = make_float4(er[4], ei[4], er[5], ei[5]);
            op[3] = make_float4(er[6], ei[6], er[7], ei[7]);
        } else {
            float4* op = (float4*)(out + N + ib);
            op[0] = make_float4(er[0], er[1], er[2], er[3]);
            op[1] = make_float4(er[4], er[5], er[6], er[7]);
        }
    }
    float nodesum = wsum;
    nodesum += __shfl_xor(nodesum, 1, 4);
    nodesum += __shfl_xor(nodesum, 2, 4);
    if (n < N && s == 0) out[n] = nodesum;  // unnormalized w
    float bv = wsum;
    #pragma unroll
    for (int off = 32; off; off >>= 1) bv += __shfl_xor(bv, off, 64);
    __shared__ float ls[TPB / 64];
    if ((threadIdx.x & 63) == 0) ls[threadIdx.x >> 6] = bv;
    __syncthreads();
    if (threadIdx.x == 0) {
        float bs = 0.f;
        #pragma unroll
        for (int i = 0; i < TPB / 64; ++i) bs += ls[i];
        partials2[blockIdx.x] = bs;
    }
}

__global__ void k_sum(const float* __restrict__ partials2, int nb,
                      float* __restrict__ S) {
    float acc = 0.f;
    for (int i = threadIdx.x; i < nb; i += blockDim.x) acc += partials2[i];
    #pragma unroll
    for (int off = 32; off; off >>= 1) acc += __shfl_xor(acc, off, 64);
    __shared__ float ls[TPB / 64];
    if ((threadIdx.x & 63) == 0) ls[threadIdx.x >> 6] = acc;
    __syncthreads();
    if (threadIdx.x == 0) {
        float s = 0.f;
        #pragma unroll
        for (int i = 0; i < TPB / 64; ++i) s += ls[i];
        *S = s;
    }
}

__global__ void k_norm(float* __restrict__ w, int N, const float* __restrict__ S) {
    int i = blockIdx.x * blockDim.x + threadIdx.x;
    if (i >= N) return;
    float s = *S;
    w[i] = (s > 1e-8f) ? w[i] * ((float)N / s) : 1.0f;
}

extern "C" void kernel_launch(void* const* d_in, const int* in_sizes, int n_in,
                              void* d_out, int out_size, void* d_ws, size_t ws_size,
                              hipStream_t stream) {
    const float* xr   = (const float*)d_in[0];
    const float* xi   = (const float*)d_in[1];
    const int*   eidx = (const int*)d_in[2];
    const float* tptr = (const float*)d_in[3];
    const float* dptr = (const float*)d_in[4];

    const int N = in_sizes[0] / 32;
    const int E = in_sizes[2] / 2;
    const int* row = eidx;
    const int* col = eidx + E;
    const long long ND = (long long)N * 32;
    const int Nw  = (N + 1) / 2;
    const int NB  = (N + 1023) / 1024;                 // scan blocks
    const int NBK = (N + 31) / 32;                     // node blocks (gather)
    const int NFB = (int)((ND / 8 + TPB - 1) / TPB);   // k_final blocks
    const int NCR = (N + CRANGE - 1) / CRANGE;
    const int NSR = (N + SRANGE - 1) / SRANGE;

    // ws allocation in 4B words, 4-word aligned chunks
    size_t o = 0;
    auto alloc = [&](size_t words) {
        o = (o + 3) & ~(size_t)3;
        size_t r = o; o += words; return r;
    };
    uint32_t* wsw = (uint32_t*)d_ws;
    uint32_t*      parts_row = wsw + alloc((size_t)BSL * Nw);
    uint32_t*      parts_col = wsw + alloc((size_t)BSL * Nw);
    unsigned char* sliceoff  = (unsigned char*)(wsw + alloc(((size_t)BSL * N + 3) / 4));
    int*           rowcnt    = (int*)(wsw + alloc(N));
    int*           rowptr    = (int*)(wsw + alloc(N + 1));
    int*           partials  = (int*)(wsw + alloc(NB));
    float*         dis       = (float*)(wsw + alloc(N));
    uint32_t*      xds       = wsw + alloc(ND);
    uint32_t*      fo2b      = wsw + alloc(ND);
    uint32_t*      fods      = wsw + alloc(ND);
    uint32_t*      delta     = wsw + alloc(ND);
    int*           ecol      = (int*)(wsw + alloc(E));
    float*         partials2 = (float*)(wsw + alloc(NFB));
    float*         S         = (float*)(wsw + alloc(1));

    int interleaved = (out_size >= (int)(N + 2 * ND)) ? 1 : 0;
    float* out = (float*)d_out;

    // --- CSR build (no global atomics) ---
    k_cnt<<<NCR * BSL, TPB, 0, stream>>>(col, E, Nw, parts_col);
    k_cnt<<<NCR * BSL, TPB, 0, stream>>>(row, E, Nw, parts_row);
    k_discol<<<(Nw + TPB - 1) / TPB, TPB, 0, stream>>>(parts_col, Nw, N, dis);
    k_redrow<<<(Nw + TPB - 1) / TPB, TPB, 0, stream>>>(parts_row, Nw, N,
                                                       sliceoff, rowcnt);
    k_scan1<<<NB, TPB, 0, stream>>>(rowcnt, rowptr, partials, N);
    k_scan2<<<1, 64, 0, stream>>>(partials, NB);
    k_scan3<<<(N + TPB - 1) / TPB, TPB, 0, stream>>>(rowptr, partials, N, E);
    k_scatter2<<<NSR * BSL, TPB, 0, stream>>>(row, col, E, N, rowptr,
                                              sliceoff, ecol);

    // --- evolution ---
    k_pack<<<(int)((ND + TPB - 1) / TPB), TPB, 0, stream>>>(xr, xi, dis, xds, N);
    int pgrid = 4 * NBK;  // slice = blockIdx.x & 3
    k_p1<<<pgrid, TPB, 0, stream>>>(rowptr, ecol, dis, xds, fo2b, fods, N);
    k_p2<<<pgrid, TPB, 0, stream>>>(rowptr, ecol, dis, fo2b, fods, tptr, dptr,
                                    delta, N);
    k_final<<<NFB, TPB, 0, stream>>>(xr, xi, delta, out, N, interleaved, partials2);
    k_sum<<<1, TPB, 0, stream>>>(partials2, NFB, S);
    k_norm<<<(N + TPB - 1) / TPB, TPB, 0, stream>>>(out, N, S);
}

// Round 10
// 212.864 us; speedup vs baseline: 1.8425x; 1.7193x over previous
//
#include <hip/hip_runtime.h>
#include <cstdint>
#include <cstddef>

// ---------------------------------------------------------------------------
// FastQuantumEvolution, dim-sliced L2-resident CSR gather.
//   dis = rsqrt(deg_col + 1)
//   prop(h)[r] = dis[r] * ( Sum_{e: row=r} h[c]*dis[c] + h[r]*dis[r] )
//   fo = prop(x); evolved = x + i*c1*fo - (c1^2/2)*prop(fo),  c1 = t*s
//   w[n] = sum_d |evolved|^2 ; w *= N / sum(w)
// CSR build, zero global atomics. R9 lesson: scatter/cnt were GRID-limited
// (416/224 blocks, 16% occupancy). R10: BSL=64 (832-block scatter), merged
// row+col count kernel (896 blocks), int4 4-wide edge streams, ws overlays.
// Output: [ w (N floats) | evolved (real-only N*32 OR interleaved N*64) ]
// ---------------------------------------------------------------------------

#define TPB 256
#define BSL 64          // edge slices
#define CRANGE 16384    // count range: packed u16 pairs -> 32KB LDS
#define SRANGE 8192     // scatter range: int cursors    -> 32KB LDS

__device__ __forceinline__ uint32_t f2bf(float f) {
    uint32_t u = __float_as_uint(f);
    return (u + 0x7FFFu + ((u >> 16) & 1u)) >> 16;  // RNE
}
__device__ __forceinline__ uint32_t pack2(float re, float im) {
    return f2bf(re) | (f2bf(im) << 16);
}
__device__ __forceinline__ float bflo(uint32_t p) { return __uint_as_float(p << 16); }
__device__ __forceinline__ float bfhi(uint32_t p) { return __uint_as_float(p & 0xFFFF0000u); }

__device__ __forceinline__ int slice_len(int E) {
    return (((E + BSL - 1) / BSL) + 3) & ~3;  // multiple of 4 for int4 loads
}

// Merged per-(range, slice) LDS histogram of col (even blocks) / row (odd).
__global__ void k_cnt2(const int* __restrict__ col, const int* __restrict__ row,
                       int E, int Nw, uint32_t* __restrict__ parts_col,
                       uint32_t* __restrict__ parts_row) {
    __shared__ uint32_t sh[CRANGE / 2];
    int which = blockIdx.x & 1;
    int rb = blockIdx.x >> 1;
    int r = rb / BSL, b = rb % BSL;
    const int* keys = which ? row : col;
    uint32_t*  parts = which ? parts_row : parts_col;
    int rbase = r * CRANGE;
    for (int i = threadIdx.x; i < CRANGE / 2; i += TPB) sh[i] = 0;
    __syncthreads();
    int SL = slice_len(E);
    int s0 = b * SL, s1 = min(E, s0 + SL);
    int n = s1 - s0;
    if (n > 0) {
        const int4* k4 = (const int4*)(keys + s0);
        int n4 = n >> 2;
        for (int j = threadIdx.x; j < n4; j += TPB) {
            int4 v = k4[j];
            int k;
            k = v.x - rbase; if ((unsigned)k < CRANGE) atomicAdd(&sh[k >> 1], 1u << ((k & 1) * 16));
            k = v.y - rbase; if ((unsigned)k < CRANGE) atomicAdd(&sh[k >> 1], 1u << ((k & 1) * 16));
            k = v.z - rbase; if ((unsigned)k < CRANGE) atomicAdd(&sh[k >> 1], 1u << ((k & 1) * 16));
            k = v.w - rbase; if ((unsigned)k < CRANGE) atomicAdd(&sh[k >> 1], 1u << ((k & 1) * 16));
        }
        for (int e = s0 + (n4 << 2) + threadIdx.x; e < s1; e += TPB) {
            int k = keys[e] - rbase;
            if ((unsigned)k < CRANGE) atomicAdd(&sh[k >> 1], 1u << ((k & 1) * 16));
        }
    }
    __syncthreads();
    int wbase = rbase >> 1;
    for (int i = threadIdx.x; i < CRANGE / 2; i += TPB) {
        int w = wbase + i;
        if (w < Nw) parts[(size_t)b * Nw + w] = sh[i];
    }
}

// dis[n] = rsqrt(col-degree + 1) from packed partials.
__global__ void k_discol(const uint32_t* __restrict__ parts, int Nw, int N,
                         float* __restrict__ dis) {
    int w = blockIdx.x * blockDim.x + threadIdx.x;
    if (w >= Nw) return;
    uint32_t lo = 0, hi = 0;
    for (int b = 0; b < BSL; ++b) {
        uint32_t v = parts[(size_t)b * Nw + w];
        lo += v & 0xFFFFu; hi += v >> 16;
    }
    int n = 2 * w;
    if (n < N)     dis[n]     = rsqrtf((float)lo + 1.0f);
    if (n + 1 < N) dis[n + 1] = rsqrtf((float)hi + 1.0f);
}

// Per-row: exclusive scan across slices -> sliceoff (u8), total -> rowcnt.
__global__ void k_redrow(const uint32_t* __restrict__ parts, int Nw, int N,
                         unsigned char* __restrict__ sliceoff,
                         int* __restrict__ rowcnt) {
    int w = blockIdx.x * blockDim.x + threadIdx.x;
    if (w >= Nw) return;
    uint32_t lo = 0, hi = 0;
    int n = 2 * w;
    for (int b = 0; b < BSL; ++b) {
        uint32_t v = parts[(size_t)b * Nw + w];
        if (n < N)     sliceoff[(size_t)b * N + n]     = (unsigned char)lo;
        if (n + 1 < N) sliceoff[(size_t)b * N + n + 1] = (unsigned char)hi;
        lo += v & 0xFFFFu; hi += v >> 16;
    }
    if (n < N)     rowcnt[n]     = (int)lo;
    if (n + 1 < N) rowcnt[n + 1] = (int)hi;
}

// exclusive scan, 1024 elems per 256-thread block
__global__ void k_scan1(const int* __restrict__ in, int* __restrict__ out,
                        int* __restrict__ partials, int N) {
    __shared__ int sh[256];
    int t = threadIdx.x;
    int base = blockIdx.x * 1024 + t * 4;
    int v0 = (base + 0 < N) ? in[base + 0] : 0;
    int v1 = (base + 1 < N) ? in[base + 1] : 0;
    int v2 = (base + 2 < N) ? in[base + 2] : 0;
    int v3 = (base + 3 < N) ? in[base + 3] : 0;
    int s = v0 + v1 + v2 + v3;
    sh[t] = s;
    __syncthreads();
    for (int off = 1; off < 256; off <<= 1) {
        int add = (t >= off) ? sh[t - off] : 0;
        __syncthreads();
        sh[t] += add;
        __syncthreads();
    }
    int excl = sh[t] - s;
    if (base + 0 < N) out[base + 0] = excl;
    excl += v0;
    if (base + 1 < N) out[base + 1] = excl;
    excl += v1;
    if (base + 2 < N) out[base + 2] = excl;
    excl += v2;
    if (base + 3 < N) out[base + 3] = excl;
    if (t == 255) partials[blockIdx.x] = sh[255];
}

__global__ void k_scan2(int* __restrict__ partials, int nb) {
    if (threadIdx.x == 0 && blockIdx.x == 0) {
        int acc = 0;
        for (int i = 0; i < nb; ++i) { int v = partials[i]; partials[i] = acc; acc += v; }
    }
}

__global__ void k_scan3(int* __restrict__ out, const int* __restrict__ partials,
                        int N, int E) {
    int i = blockIdx.x * blockDim.x + threadIdx.x;
    if (i < N) out[i] += partials[i >> 10];
    if (i == 0) out[N] = E;
}

// Scatter with LDS cursors initialized to rowptr + sliceoff; one LDS atomic
// per in-range edge, plain global store. Zero global atomics. int4 streams.
__global__ void k_scatter2(const int* __restrict__ row, const int* __restrict__ col,
                           int E, int N, const int* __restrict__ rowptr,
                           const unsigned char* __restrict__ sliceoff,
                           int* __restrict__ ecol) {
    __shared__ int cur[SRANGE];
    int r = blockIdx.x / BSL, b = blockIdx.x % BSL;
    int rbase = r * SRANGE;
    for (int i = threadIdx.x; i < SRANGE; i += TPB) {
        int n = rbase + i;
        cur[i] = (n < N) ? rowptr[n] + (int)sliceoff[(size_t)b * N + n] : 0;
    }
    __syncthreads();
    int SL = slice_len(E);
    int s0 = b * SL, s1 = min(E, s0 + SL);
    int n = s1 - s0;
    if (n <= 0) return;
    const int4* r4 = (const int4*)(row + s0);
    const int4* c4 = (const int4*)(col + s0);
    int n4 = n >> 2;
    for (int j = threadIdx.x; j < n4; j += TPB) {
        int4 rv = r4[j];
        int4 cv = c4[j];
        int rr;
        rr = rv.x - rbase; if ((unsigned)rr < SRANGE) ecol[atomicAdd(&cur[rr], 1)] = cv.x;
        rr = rv.y - rbase; if ((unsigned)rr < SRANGE) ecol[atomicAdd(&cur[rr], 1)] = cv.y;
        rr = rv.z - rbase; if ((unsigned)rr < SRANGE) ecol[atomicAdd(&cur[rr], 1)] = cv.z;
        rr = rv.w - rbase; if ((unsigned)rr < SRANGE) ecol[atomicAdd(&cur[rr], 1)] = cv.w;
    }
    for (int e = s0 + (n4 << 2) + threadIdx.x; e < s1; e += TPB) {
        int rr = row[e] - rbase;
        if ((unsigned)rr < SRANGE) ecol[atomicAdd(&cur[rr], 1)] = col[e];
    }
}

// xds[s][n][dd] = pack2(x*dis) for dim k = 8s+dd  (sliced, premultiplied)
__global__ void k_pack(const float* __restrict__ xr, const float* __restrict__ xi,
                       const float* __restrict__ dis, uint32_t* __restrict__ xds,
                       int N) {
    int i = blockIdx.x * blockDim.x + threadIdx.x;
    if (i < N * 32) {
        int n = i >> 5, k = i & 31, s = k >> 3, dd = k & 7;
        float dg = dis[n];
        xds[((size_t)s * N + n) * 8 + dd] = pack2(xr[i] * dg, xi[i] * dg);
    }
}

// Gather-accumulate over one node's edges from an 8-dim slice operand.
// 8-lane group per node; lane dd owns dim dd. 16 gathers in flight.
__device__ __forceinline__ void edge_accum8(const int* __restrict__ ecol,
                                            const uint32_t* __restrict__ hb,
                                            int beg, int end, int dd,
                                            float& aR, float& aI) {
    for (int base = beg; base < end; base += 16) {
        int m = end - base;
        int c0 = (dd < m)     ? ecol[base + dd]     : -1;
        int c1 = (8 + dd < m) ? ecol[base + 8 + dd] : -1;
        int cc[16];
        uint32_t p[16];
        #pragma unroll
        for (int k = 0; k < 8; ++k) {
            cc[k]     = __shfl(c0, k, 8);
            cc[k + 8] = __shfl(c1, k, 8);
        }
        #pragma unroll
        for (int k = 0; k < 16; ++k) {
            int c = cc[k] < 0 ? 0 : cc[k];
            p[k] = hb[c * 8 + dd];
        }
        #pragma unroll
        for (int k = 0; k < 16; ++k)
            if (cc[k] >= 0) { aR += bflo(p[k]); aI += bfhi(p[k]); }
    }
}

// Pass 1: fo = dis*(sum + self). Writes fo2b (bf16 fo) + fods (bf16 fo*dis).
__global__ void k_p1(const int* __restrict__ rowptr, const int* __restrict__ ecol,
                     const float* __restrict__ dis, const uint32_t* __restrict__ xds,
                     uint32_t* __restrict__ fo2b, uint32_t* __restrict__ fods, int N) {
    int s  = blockIdx.x & 3;
    int nb = blockIdx.x >> 2;
    int r  = nb * 32 + (threadIdx.x >> 3);
    int dd = threadIdx.x & 7;
    if (r >= N) return;
    const uint32_t* hb = xds + (size_t)s * N * 8;
    int beg = rowptr[r], end = rowptr[r + 1];
    float dg = dis[r];
    float aR = 0.f, aI = 0.f;
    edge_accum8(ecol, hb, beg, end, dd, aR, aI);
    uint32_t sv = hb[r * 8 + dd];  // self loop: x[r]*dis[r] (premultiplied)
    aR += bflo(sv); aI += bfhi(sv);
    float foR = dg * aR, foI = dg * aI;
    size_t o = (size_t)s * N * 8 + (size_t)r * 8 + dd;
    fo2b[o] = pack2(foR, foI);
    fods[o] = pack2(foR * dg, foI * dg);  // premultiplied for pass 2
}

// Pass 2: so = dis*(sum + self); delta = (-c1*foI - c2h*soR, c1*foR - c2h*soI).
__global__ void k_p2(const int* __restrict__ rowptr, const int* __restrict__ ecol,
                     const float* __restrict__ dis, const uint32_t* __restrict__ fo2b,
                     const uint32_t* __restrict__ fods,
                     const float* __restrict__ tptr, const float* __restrict__ dptr,
                     uint32_t* __restrict__ delta, int N) {
    int s  = blockIdx.x & 3;
    int nb = blockIdx.x >> 2;
    int r  = nb * 32 + (threadIdx.x >> 3);
    int dd = threadIdx.x & 7;
    if (r >= N) return;
    const uint32_t* hb = fods + (size_t)s * N * 8;
    int beg = rowptr[r], end = rowptr[r + 1];
    float dg = dis[r];
    float aR = 0.f, aI = 0.f;
    edge_accum8(ecol, hb, beg, end, dd, aR, aI);
    uint32_t sv = hb[r * 8 + dd];  // self loop: fo[r]*dis[r]
    aR += bflo(sv); aI += bfhi(sv);
    float soR = dg * aR, soI = dg * aI;
    size_t o = (size_t)s * N * 8 + (size_t)r * 8 + dd;
    uint32_t fp = fo2b[o];
    float foR = bflo(fp), foI = bfhi(fp);
    float c1  = tptr[0] * dptr[0];
    float c2h = 0.5f * c1 * c1;
    delta[o] = pack2(-c1 * foI - c2h * soR, c1 * foR - c2h * soI);
}

// Final: evolved = x + delta (exact f32 base), per-node w, per-BLOCK partial
// (plain store). One thread = (node n, slice s) = 8 dims.
__global__ void k_final(const float* __restrict__ xr, const float* __restrict__ xi,
                        const uint32_t* __restrict__ delta, float* __restrict__ out,
                        int N, int interleaved, float* __restrict__ partials2) {
    int t = blockIdx.x * blockDim.x + threadIdx.x;
    int n = t >> 2, s = t & 3;
    float wsum = 0.f;
    if (n < N) {
        const uint4* dp = (const uint4*)(delta + ((size_t)s * N + n) * 8);
        uint4 d0 = dp[0], d1 = dp[1];
        size_t ib = (size_t)n * 32 + (size_t)s * 8;
        const float4* xr4 = (const float4*)(xr + ib);
        const float4* xi4 = (const float4*)(xi + ib);
        float4 a0 = xr4[0], a1 = xr4[1];
        float4 b0 = xi4[0], b1 = xi4[1];
        uint32_t dv[8] = {d0.x, d0.y, d0.z, d0.w, d1.x, d1.y, d1.z, d1.w};
        float ar[8] = {a0.x, a0.y, a0.z, a0.w, a1.x, a1.y, a1.z, a1.w};
        float ai[8] = {b0.x, b0.y, b0.z, b0.w, b1.x, b1.y, b1.z, b1.w};
        float er[8], ei[8];
        #pragma unroll
        for (int k = 0; k < 8; ++k) {
            er[k] = ar[k] + bflo(dv[k]);
            ei[k] = ai[k] + bfhi(dv[k]);
            wsum += er[k] * er[k] + ei[k] * ei[k];
        }
        if (interleaved) {
            float4* op = (float4*)(out + N + 2 * ib);
            op[0] = make_float4(er[0], ei[0], er[1], ei[1]);
            op[1] = make_float4(er[2], ei[2], er[3], ei[3]);
            op[2] = make_float4(er[4], ei[4], er[5], ei[5]);
            op[3] = make_float4(er[6], ei[6], er[7], ei[7]);
        } else {
            float4* op = (float4*)(out + N + ib);
            op[0] = make_float4(er[0], er[1], er[2], er[3]);
            op[1] = make_float4(er[4], er[5], er[6], er[7]);
        }
    }
    float nodesum = wsum;
    nodesum += __shfl_xor(nodesum, 1, 4);
    nodesum += __shfl_xor(nodesum, 2, 4);
    if (n < N && s == 0) out[n] = nodesum;  // unnormalized w
    float bv = wsum;
    #pragma unroll
    for (int off = 32; off; off >>= 1) bv += __shfl_xor(bv, off, 64);
    __shared__ float ls[TPB / 64];
    if ((threadIdx.x & 63) == 0) ls[threadIdx.x >> 6] = bv;
    __syncthreads();
    if (threadIdx.x == 0) {
        float bs = 0.f;
        #pragma unroll
        for (int i = 0; i < TPB / 64; ++i) bs += ls[i];
        partials2[blockIdx.x] = bs;
    }
}

__global__ void k_sum(const float* __restrict__ partials2, int nb,
                      float* __restrict__ S) {
    float acc = 0.f;
    for (int i = threadIdx.x; i < nb; i += blockDim.x) acc += partials2[i];
    #pragma unroll
    for (int off = 32; off; off >>= 1) acc += __shfl_xor(acc, off, 64);
    __shared__ float ls[TPB / 64];
    if ((threadIdx.x & 63) == 0) ls[threadIdx.x >> 6] = acc;
    __syncthreads();
    if (threadIdx.x == 0) {
        float s = 0.f;
        #pragma unroll
        for (int i = 0; i < TPB / 64; ++i) s += ls[i];
        *S = s;
    }
}

__global__ void k_norm(float* __restrict__ w, int N, const float* __restrict__ S) {
    int i = blockIdx.x * blockDim.x + threadIdx.x;
    if (i >= N) return;
    float s = *S;
    w[i] = (s > 1e-8f) ? w[i] * ((float)N / s) : 1.0f;
}

extern "C" void kernel_launch(void* const* d_in, const int* in_sizes, int n_in,
                              void* d_out, int out_size, void* d_ws, size_t ws_size,
                              hipStream_t stream) {
    const float* xr   = (const float*)d_in[0];
    const float* xi   = (const float*)d_in[1];
    const int*   eidx = (const int*)d_in[2];
    const float* tptr = (const float*)d_in[3];
    const float* dptr = (const float*)d_in[4];

    const int N = in_sizes[0] / 32;
    const int E = in_sizes[2] / 2;
    const int* row = eidx;
    const int* col = eidx + E;
    const long long ND = (long long)N * 32;
    const int Nw  = (N + 1) / 2;
    const int NB  = (N + 1023) / 1024;                 // scan blocks
    const int NBK = (N + 31) / 32;                     // node blocks (gather)
    const int NFB = (int)((ND / 8 + TPB - 1) / TPB);   // k_final blocks
    const int NCR = (N + CRANGE - 1) / CRANGE;
    const int NSR = (N + SRANGE - 1) / SRANGE;

    // ws allocation in 4B words, 4-word aligned chunks.
    // Overlays: ecol aliases parts_col (dead after k_discol);
    //           delta aliases parts_row (dead after k_redrow).
    size_t o = 0;
    auto alloc = [&](size_t words) {
        o = (o + 3) & ~(size_t)3;
        size_t r = o; o += words; return r;
    };
    uint32_t* wsw = (uint32_t*)d_ws;
    uint32_t*      parts_row = wsw + alloc((size_t)BSL * Nw);
    uint32_t*      parts_col = wsw + alloc((size_t)BSL * Nw);
    unsigned char* sliceoff  = (unsigned char*)(wsw + alloc(((size_t)BSL * N + 3) / 4));
    int*           rowcnt    = (int*)(wsw + alloc(N));
    int*           rowptr    = (int*)(wsw + alloc(N + 1));
    int*           partials  = (int*)(wsw + alloc(NB));
    float*         dis       = (float*)(wsw + alloc(N));
    uint32_t*      xds       = wsw + alloc(ND);
    uint32_t*      fo2b      = wsw + alloc(ND);
    uint32_t*      fods      = wsw + alloc(ND);
    float*         partials2 = (float*)(wsw + alloc(NFB));
    float*         S         = (float*)(wsw + alloc(1));
    uint32_t*      delta     = parts_row;          // overlay (ND == BSL*Nw)
    int*           ecol      = (int*)parts_col;    // overlay (E <= BSL*Nw)

    int interleaved = (out_size >= (int)(N + 2 * ND)) ? 1 : 0;
    float* out = (float*)d_out;

    // --- CSR build (no global atomics) ---
    k_cnt2<<<NCR * BSL * 2, TPB, 0, stream>>>(col, row, E, Nw, parts_col, parts_row);
    k_discol<<<(Nw + TPB - 1) / TPB, TPB, 0, stream>>>(parts_col, Nw, N, dis);
    k_redrow<<<(Nw + TPB - 1) / TPB, TPB, 0, stream>>>(parts_row, Nw, N,
                                                       sliceoff, rowcnt);
    k_scan1<<<NB, TPB, 0, stream>>>(rowcnt, rowptr, partials, N);
    k_scan2<<<1, 64, 0, stream>>>(partials, NB);
    k_scan3<<<(N + TPB - 1) / TPB, TPB, 0, stream>>>(rowptr, partials, N, E);
    k_scatter2<<<NSR * BSL, TPB, 0, stream>>>(row, col, E, N, rowptr,
                                              sliceoff, ecol);

    // --- evolution ---
    k_pack<<<(int)((ND + TPB - 1) / TPB), TPB, 0, stream>>>(xr, xi, dis, xds, N);
    int pgrid = 4 * NBK;  // slice = blockIdx.x & 3
    k_p1<<<pgrid, TPB, 0, stream>>>(rowptr, ecol, dis, xds, fo2b, fods, N);
    k_p2<<<pgrid, TPB, 0, stream>>>(rowptr, ecol, dis, fo2b, fods, tptr, dptr,
                                    delta, N);
    k_final<<<NFB, TPB, 0, stream>>>(xr, xi, delta, out, N, interleaved, partials2);
    k_sum<<<1, TPB, 0, stream>>>(partials2, NFB, S);
    k_norm<<<(N + TPB - 1) / TPB, TPB, 0, stream>>>(out, N, S);
}

// Round 11
// 209.038 us; speedup vs baseline: 1.8762x; 1.0183x over previous
//
#include <hip/hip_runtime.h>
#include <cstdint>
#include <cstddef>

// ---------------------------------------------------------------------------
// FastQuantumEvolution, dim-sliced L2-resident CSR gather, fp16+dot2 accum.
//   dis = rsqrt(deg_col + 1)
//   prop(h)[r] = dis[r] * ( Sum_{e: row=r} h[c]*dis[c] + h[r]*dis[r] )
//   fo = prop(x); evolved = x + i*c1*fo - (c1^2/2)*prop(fo),  c1 = t*s
//   w[n] = sum_d |evolved|^2 ; w *= N / sum(w)
// R11: packed operands are fp16 pairs (re,im); per-edge accumulation via
// v_dot2_f32_f16 (1 VALU per component vs unpack+add), invalid edges zeroed
// with one cndmask. CSR build unchanged from R10 (zero global atomics,
// BSL=64, int4 streams).
// Output: [ w (N floats) | evolved (real-only N*32 OR interleaved N*64) ]
// ---------------------------------------------------------------------------

#define TPB 256
#define BSL 64          // edge slices
#define CRANGE 16384    // count range: packed u16 pairs -> 32KB LDS
#define SRANGE 8192     // scatter range: int cursors    -> 32KB LDS

typedef _Float16 h2 __attribute__((ext_vector_type(2)));

#if defined(__has_builtin)
#if __has_builtin(__builtin_amdgcn_fdot2)
#define HAS_FDOT2 1
#endif
#endif

__device__ __forceinline__ h2 u2h(uint32_t u) {
    union { uint32_t u; h2 h; } x; x.u = u; return x.h;
}
__device__ __forceinline__ uint32_t h2u(h2 h) {
    union { uint32_t u; h2 h; } x; x.h = h; return x.u;
}
__device__ __forceinline__ uint32_t packh(float re, float im) {
    h2 h; h.x = (_Float16)re; h.y = (_Float16)im; return h2u(h);
}
__device__ __forceinline__ void acc2(uint32_t p, float& aR, float& aI) {
#ifdef HAS_FDOT2
    h2 v = u2h(p);
    h2 LO; LO.x = (_Float16)1.0f; LO.y = (_Float16)0.0f;
    h2 HI; HI.x = (_Float16)0.0f; HI.y = (_Float16)1.0f;
    aR = __builtin_amdgcn_fdot2(v, LO, aR, false);
    aI = __builtin_amdgcn_fdot2(v, HI, aI, false);
#else
    h2 v = u2h(p);
    aR += (float)v.x;
    aI += (float)v.y;
#endif
}

__device__ __forceinline__ int slice_len(int E) {
    return (((E + BSL - 1) / BSL) + 3) & ~3;  // multiple of 4 for int4 loads
}

// Merged per-(range, slice) LDS histogram of col (even blocks) / row (odd).
__global__ void k_cnt2(const int* __restrict__ col, const int* __restrict__ row,
                       int E, int Nw, uint32_t* __restrict__ parts_col,
                       uint32_t* __restrict__ parts_row) {
    __shared__ uint32_t sh[CRANGE / 2];
    int which = blockIdx.x & 1;
    int rb = blockIdx.x >> 1;
    int r = rb / BSL, b = rb % BSL;
    const int* keys = which ? row : col;
    uint32_t*  parts = which ? parts_row : parts_col;
    int rbase = r * CRANGE;
    for (int i = threadIdx.x; i < CRANGE / 2; i += TPB) sh[i] = 0;
    __syncthreads();
    int SL = slice_len(E);
    int s0 = b * SL, s1 = min(E, s0 + SL);
    int n = s1 - s0;
    if (n > 0) {
        const int4* k4 = (const int4*)(keys + s0);
        int n4 = n >> 2;
        for (int j = threadIdx.x; j < n4; j += TPB) {
            int4 v = k4[j];
            int k;
            k = v.x - rbase; if ((unsigned)k < CRANGE) atomicAdd(&sh[k >> 1], 1u << ((k & 1) * 16));
            k = v.y - rbase; if ((unsigned)k < CRANGE) atomicAdd(&sh[k >> 1], 1u << ((k & 1) * 16));
            k = v.z - rbase; if ((unsigned)k < CRANGE) atomicAdd(&sh[k >> 1], 1u << ((k & 1) * 16));
            k = v.w - rbase; if ((unsigned)k < CRANGE) atomicAdd(&sh[k >> 1], 1u << ((k & 1) * 16));
        }
        for (int e = s0 + (n4 << 2) + threadIdx.x; e < s1; e += TPB) {
            int k = keys[e] - rbase;
            if ((unsigned)k < CRANGE) atomicAdd(&sh[k >> 1], 1u << ((k & 1) * 16));
        }
    }
    __syncthreads();
    int wbase = rbase >> 1;
    for (int i = threadIdx.x; i < CRANGE / 2; i += TPB) {
        int w = wbase + i;
        if (w < Nw) parts[(size_t)b * Nw + w] = sh[i];
    }
}

// dis[n] = rsqrt(col-degree + 1) from packed partials.
__global__ void k_discol(const uint32_t* __restrict__ parts, int Nw, int N,
                         float* __restrict__ dis) {
    int w = blockIdx.x * blockDim.x + threadIdx.x;
    if (w >= Nw) return;
    uint32_t lo = 0, hi = 0;
    for (int b = 0; b < BSL; ++b) {
        uint32_t v = parts[(size_t)b * Nw + w];
        lo += v & 0xFFFFu; hi += v >> 16;
    }
    int n = 2 * w;
    if (n < N)     dis[n]     = rsqrtf((float)lo + 1.0f);
    if (n + 1 < N) dis[n + 1] = rsqrtf((float)hi + 1.0f);
}

// Per-row: exclusive scan across slices -> sliceoff (u8), total -> rowcnt.
__global__ void k_redrow(const uint32_t* __restrict__ parts, int Nw, int N,
                         unsigned char* __restrict__ sliceoff,
                         int* __restrict__ rowcnt) {
    int w = blockIdx.x * blockDim.x + threadIdx.x;
    if (w >= Nw) return;
    uint32_t lo = 0, hi = 0;
    int n = 2 * w;
    for (int b = 0; b < BSL; ++b) {
        uint32_t v = parts[(size_t)b * Nw + w];
        if (n < N)     sliceoff[(size_t)b * N + n]     = (unsigned char)lo;
        if (n + 1 < N) sliceoff[(size_t)b * N + n + 1] = (unsigned char)hi;
        lo += v & 0xFFFFu; hi += v >> 16;
    }
    if (n < N)     rowcnt[n]     = (int)lo;
    if (n + 1 < N) rowcnt[n + 1] = (int)hi;
}

// exclusive scan, 1024 elems per 256-thread block
__global__ void k_scan1(const int* __restrict__ in, int* __restrict__ out,
                        int* __restrict__ partials, int N) {
    __shared__ int sh[256];
    int t = threadIdx.x;
    int base = blockIdx.x * 1024 + t * 4;
    int v0 = (base + 0 < N) ? in[base + 0] : 0;
    int v1 = (base + 1 < N) ? in[base + 1] : 0;
    int v2 = (base + 2 < N) ? in[base + 2] : 0;
    int v3 = (base + 3 < N) ? in[base + 3] : 0;
    int s = v0 + v1 + v2 + v3;
    sh[t] = s;
    __syncthreads();
    for (int off = 1; off < 256; off <<= 1) {
        int add = (t >= off) ? sh[t - off] : 0;
        __syncthreads();
        sh[t] += add;
        __syncthreads();
    }
    int excl = sh[t] - s;
    if (base + 0 < N) out[base + 0] = excl;
    excl += v0;
    if (base + 1 < N) out[base + 1] = excl;
    excl += v1;
    if (base + 2 < N) out[base + 2] = excl;
    excl += v2;
    if (base + 3 < N) out[base + 3] = excl;
    if (t == 255) partials[blockIdx.x] = sh[255];
}

__global__ void k_scan2(int* __restrict__ partials, int nb) {
    if (threadIdx.x == 0 && blockIdx.x == 0) {
        int acc = 0;
        for (int i = 0; i < nb; ++i) { int v = partials[i]; partials[i] = acc; acc += v; }
    }
}

__global__ void k_scan3(int* __restrict__ out, const int* __restrict__ partials,
                        int N, int E) {
    int i = blockIdx.x * blockDim.x + threadIdx.x;
    if (i < N) out[i] += partials[i >> 10];
    if (i == 0) out[N] = E;
}

// Scatter with LDS cursors initialized to rowptr + sliceoff; one LDS atomic
// per in-range edge, plain global store. Zero global atomics. int4 streams.
__global__ void k_scatter2(const int* __restrict__ row, const int* __restrict__ col,
                           int E, int N, const int* __restrict__ rowptr,
                           const unsigned char* __restrict__ sliceoff,
                           int* __restrict__ ecol) {
    __shared__ int cur[SRANGE];
    int r = blockIdx.x / BSL, b = blockIdx.x % BSL;
    int rbase = r * SRANGE;
    for (int i = threadIdx.x; i < SRANGE; i += TPB) {
        int n = rbase + i;
        cur[i] = (n < N) ? rowptr[n] + (int)sliceoff[(size_t)b * N + n] : 0;
    }
    __syncthreads();
    int SL = slice_len(E);
    int s0 = b * SL, s1 = min(E, s0 + SL);
    int n = s1 - s0;
    if (n <= 0) return;
    const int4* r4 = (const int4*)(row + s0);
    const int4* c4 = (const int4*)(col + s0);
    int n4 = n >> 2;
    for (int j = threadIdx.x; j < n4; j += TPB) {
        int4 rv = r4[j];
        int4 cv = c4[j];
        int rr;
        rr = rv.x - rbase; if ((unsigned)rr < SRANGE) ecol[atomicAdd(&cur[rr], 1)] = cv.x;
        rr = rv.y - rbase; if ((unsigned)rr < SRANGE) ecol[atomicAdd(&cur[rr], 1)] = cv.y;
        rr = rv.z - rbase; if ((unsigned)rr < SRANGE) ecol[atomicAdd(&cur[rr], 1)] = cv.z;
        rr = rv.w - rbase; if ((unsigned)rr < SRANGE) ecol[atomicAdd(&cur[rr], 1)] = cv.w;
    }
    for (int e = s0 + (n4 << 2) + threadIdx.x; e < s1; e += TPB) {
        int rr = row[e] - rbase;
        if ((unsigned)rr < SRANGE) ecol[atomicAdd(&cur[rr], 1)] = col[e];
    }
}

// xds[s][n][dd] = packh(x*dis) for dim k = 8s+dd  (sliced, premultiplied)
__global__ void k_pack(const float* __restrict__ xr, const float* __restrict__ xi,
                       const float* __restrict__ dis, uint32_t* __restrict__ xds,
                       int N) {
    int i = blockIdx.x * blockDim.x + threadIdx.x;
    if (i < N * 32) {
        int n = i >> 5, k = i & 31, s = k >> 3, dd = k & 7;
        float dg = dis[n];
        xds[((size_t)s * N + n) * 8 + dd] = packh(xr[i] * dg, xi[i] * dg);
    }
}

// Gather-accumulate over one node's edges from an 8-dim slice operand.
// 8-lane group per node; lane dd owns dim dd. 16 gathers in flight.
// Invalid (pad) edges: gathered word zeroed with one cndmask -> dot2s
// are unconditional.
__device__ __forceinline__ void edge_accum8(const int* __restrict__ ecol,
                                            const uint32_t* __restrict__ hb,
                                            int beg, int end, int dd,
                                            float& aR, float& aI) {
    for (int base = beg; base < end; base += 16) {
        int m = end - base;
        int c0 = (dd < m)     ? ecol[base + dd]     : -1;
        int c1 = (8 + dd < m) ? ecol[base + 8 + dd] : -1;
        int cc[16];
        uint32_t p[16];
        #pragma unroll
        for (int k = 0; k < 8; ++k) {
            cc[k]     = __shfl(c0, k, 8);
            cc[k + 8] = __shfl(c1, k, 8);
        }
        #pragma unroll
        for (int k = 0; k < 16; ++k) {
            int c = cc[k] < 0 ? 0 : cc[k];
            uint32_t v = hb[(size_t)c * 8 + dd];
            p[k] = (cc[k] < 0) ? 0u : v;
        }
        #pragma unroll
        for (int k = 0; k < 16; ++k) acc2(p[k], aR, aI);
    }
}

// Pass 1: fo = dis*(sum + self). Writes fo2b (fp16 fo) + fods (fp16 fo*dis).
__global__ void k_p1(const int* __restrict__ rowptr, const int* __restrict__ ecol,
                     const float* __restrict__ dis, const uint32_t* __restrict__ xds,
                     uint32_t* __restrict__ fo2b, uint32_t* __restrict__ fods, int N) {
    int s  = blockIdx.x & 3;
    int nb = blockIdx.x >> 2;
    int r  = nb * 32 + (threadIdx.x >> 3);
    int dd = threadIdx.x & 7;
    if (r >= N) return;
    const uint32_t* hb = xds + (size_t)s * N * 8;
    int beg = rowptr[r], end = rowptr[r + 1];
    float dg = dis[r];
    float aR = 0.f, aI = 0.f;
    edge_accum8(ecol, hb, beg, end, dd, aR, aI);
    acc2(hb[(size_t)r * 8 + dd], aR, aI);  // self loop: x[r]*dis[r]
    float foR = dg * aR, foI = dg * aI;
    size_t o = (size_t)s * N * 8 + (size_t)r * 8 + dd;
    fo2b[o] = packh(foR, foI);
    fods[o] = packh(foR * dg, foI * dg);  // premultiplied for pass 2
}

// Pass 2: so = dis*(sum + self); delta = (-c1*foI - c2h*soR, c1*foR - c2h*soI).
__global__ void k_p2(const int* __restrict__ rowptr, const int* __restrict__ ecol,
                     const float* __restrict__ dis, const uint32_t* __restrict__ fo2b,
                     const uint32_t* __restrict__ fods,
                     const float* __restrict__ tptr, const float* __restrict__ dptr,
                     uint32_t* __restrict__ delta, int N) {
    int s  = blockIdx.x & 3;
    int nb = blockIdx.x >> 2;
    int r  = nb * 32 + (threadIdx.x >> 3);
    int dd = threadIdx.x & 7;
    if (r >= N) return;
    const uint32_t* hb = fods + (size_t)s * N * 8;
    int beg = rowptr[r], end = rowptr[r + 1];
    float dg = dis[r];
    float aR = 0.f, aI = 0.f;
    edge_accum8(ecol, hb, beg, end, dd, aR, aI);
    acc2(hb[(size_t)r * 8 + dd], aR, aI);  // self loop: fo[r]*dis[r]
    float soR = dg * aR, soI = dg * aI;
    size_t o = (size_t)s * N * 8 + (size_t)r * 8 + dd;
    h2 f = u2h(fo2b[o]);
    float foR = (float)f.x, foI = (float)f.y;
    float c1  = tptr[0] * dptr[0];
    float c2h = 0.5f * c1 * c1;
    delta[o] = packh(-c1 * foI - c2h * soR, c1 * foR - c2h * soI);
}

// Final: evolved = x + delta (exact f32 base), per-node w, per-BLOCK partial
// (plain store). One thread = (node n, slice s) = 8 dims.
__global__ void k_final(const float* __restrict__ xr, const float* __restrict__ xi,
                        const uint32_t* __restrict__ delta, float* __restrict__ out,
                        int N, int interleaved, float* __restrict__ partials2) {
    int t = blockIdx.x * blockDim.x + threadIdx.x;
    int n = t >> 2, s = t & 3;
    float wsum = 0.f;
    if (n < N) {
        const uint4* dp = (const uint4*)(delta + ((size_t)s * N + n) * 8);
        uint4 d0 = dp[0], d1 = dp[1];
        size_t ib = (size_t)n * 32 + (size_t)s * 8;
        const float4* xr4 = (const float4*)(xr + ib);
        const float4* xi4 = (const float4*)(xi + ib);
        float4 a0 = xr4[0], a1 = xr4[1];
        float4 b0 = xi4[0], b1 = xi4[1];
        uint32_t dv[8] = {d0.x, d0.y, d0.z, d0.w, d1.x, d1.y, d1.z, d1.w};
        float ar[8] = {a0.x, a0.y, a0.z, a0.w, a1.x, a1.y, a1.z, a1.w};
        float ai[8] = {b0.x, b0.y, b0.z, b0.w, b1.x, b1.y, b1.z, b1.w};
        float er[8], ei[8];
        #pragma unroll
        for (int k = 0; k < 8; ++k) {
            h2 d = u2h(dv[k]);
            er[k] = ar[k] + (float)d.x;
            ei[k] = ai[k] + (float)d.y;
            wsum += er[k] * er[k] + ei[k] * ei[k];
        }
        if (interleaved) {
            float4* op = (float4*)(out + N + 2 * ib);
            op[0] = make_float4(er[0], ei[0], er[1], ei[1]);
            op[1] = make_float4(er[2], ei[2], er[3], ei[3]);
            op[2] = make_float4(er[4], ei[4], er[5], ei[5]);
            op[3] = make_float4(er[6], ei[6], er[7], ei[7]);
        } else {
            float4* op = (float4*)(out + N + ib);
            op[0] = make_float4(er[0], er[1], er[2], er[3]);
            op[1] = make_float4(er[4], er[5], er[6], er[7]);
        }
    }
    float nodesum = wsum;
    nodesum += __shfl_xor(nodesum, 1, 4);
    nodesum += __shfl_xor(nodesum, 2, 4);
    if (n < N && s == 0) out[n] = nodesum;  // unnormalized w
    float bv = wsum;
    #pragma unroll
    for (int off = 32; off; off >>= 1) bv += __shfl_xor(bv, off, 64);
    __shared__ float ls[TPB / 64];
    if ((threadIdx.x & 63) == 0) ls[threadIdx.x >> 6] = bv;
    __syncthreads();
    if (threadIdx.x == 0) {
        float bs = 0.f;
        #pragma unroll
        for (int i = 0; i < TPB / 64; ++i) bs += ls[i];
        partials2[blockIdx.x] = bs;
    }
}

__global__ void k_sum(const float* __restrict__ partials2, int nb,
                      float* __restrict__ S) {
    float acc = 0.f;
    for (int i = threadIdx.x; i < nb; i += blockDim.x) acc += partials2[i];
    #pragma unroll
    for (int off = 32; off; off >>= 1) acc += __shfl_xor(acc, off, 64);
    __shared__ float ls[TPB / 64];
    if ((threadIdx.x & 63) == 0) ls[threadIdx.x >> 6] = acc;
    __syncthreads();
    if (threadIdx.x == 0) {
        float s = 0.f;
        #pragma unroll
        for (int i = 0; i < TPB / 64; ++i) s += ls[i];
        *S = s;
    }
}

__global__ void k_norm(float* __restrict__ w, int N, const float* __restrict__ S) {
    int i = blockIdx.x * blockDim.x + threadIdx.x;
    if (i >= N) return;
    float s = *S;
    w[i] = (s > 1e-8f) ? w[i] * ((float)N / s) : 1.0f;
}

extern "C" void kernel_launch(void* const* d_in, const int* in_sizes, int n_in,
                              void* d_out, int out_size, void* d_ws, size_t ws_size,
                              hipStream_t stream) {
    const float* xr   = (const float*)d_in[0];
    const float* xi   = (const float*)d_in[1];
    const int*   eidx = (const int*)d_in[2];
    const float* tptr = (const float*)d_in[3];
    const float* dptr = (const float*)d_in[4];

    const int N = in_sizes[0] / 32;
    const int E = in_sizes[2] / 2;
    const int* row = eidx;
    const int* col = eidx + E;
    const long long ND = (long long)N * 32;
    const int Nw  = (N + 1) / 2;
    const int NB  = (N + 1023) / 1024;                 // scan blocks
    const int NBK = (N + 31) / 32;                     // node blocks (gather)
    const int NFB = (int)((ND / 8 + TPB - 1) / TPB);   // k_final blocks
    const int NCR = (N + CRANGE - 1) / CRANGE;
    const int NSR = (N + SRANGE - 1) / SRANGE;

    // ws allocation in 4B words, 4-word aligned chunks.
    // Overlays: ecol aliases parts_col (dead after k_discol);
    //           delta aliases parts_row (dead after k_redrow).
    size_t o = 0;
    auto alloc = [&](size_t words) {
        o = (o + 3) & ~(size_t)3;
        size_t r = o; o += words; return r;
    };
    uint32_t* wsw = (uint32_t*)d_ws;
    uint32_t*      parts_row = wsw + alloc((size_t)BSL * Nw);
    uint32_t*      parts_col = wsw + alloc((size_t)BSL * Nw);
    unsigned char* sliceoff  = (unsigned char*)(wsw + alloc(((size_t)BSL * N + 3) / 4));
    int*           rowcnt    = (int*)(wsw + alloc(N));
    int*           rowptr    = (int*)(wsw + alloc(N + 1));
    int*           partials  = (int*)(wsw + alloc(NB));
    float*         dis       = (float*)(wsw + alloc(N));
    uint32_t*      xds       = wsw + alloc(ND);
    uint32_t*      fo2b      = wsw + alloc(ND);
    uint32_t*      fods      = wsw + alloc(ND);
    float*         partials2 = (float*)(wsw + alloc(NFB));
    float*         S         = (float*)(wsw + alloc(1));
    uint32_t*      delta     = parts_row;          // overlay (ND == BSL*Nw)
    int*           ecol      = (int*)parts_col;    // overlay (E <= BSL*Nw)

    int interleaved = (out_size >= (int)(N + 2 * ND)) ? 1 : 0;
    float* out = (float*)d_out;

    // --- CSR build (no global atomics) ---
    k_cnt2<<<NCR * BSL * 2, TPB, 0, stream>>>(col, row, E, Nw, parts_col, parts_row);
    k_discol<<<(Nw + TPB - 1) / TPB, TPB, 0, stream>>>(parts_col, Nw, N, dis);
    k_redrow<<<(Nw + TPB - 1) / TPB, TPB, 0, stream>>>(parts_row, Nw, N,
                                                       sliceoff, rowcnt);
    k_scan1<<<NB, TPB, 0, stream>>>(rowcnt, rowptr, partials, N);
    k_scan2<<<1, 64, 0, stream>>>(partials, NB);
    k_scan3<<<(N + TPB - 1) / TPB, TPB, 0, stream>>>(rowptr, partials, N, E);
    k_scatter2<<<NSR * BSL, TPB, 0, stream>>>(row, col, E, N, rowptr,
                                              sliceoff, ecol);

    // --- evolution ---
    k_pack<<<(int)((ND + TPB - 1) / TPB), TPB, 0, stream>>>(xr, xi, dis, xds, N);
    int pgrid = 4 * NBK;  // slice = blockIdx.x & 3
    k_p1<<<pgrid, TPB, 0, stream>>>(rowptr, ecol, dis, xds, fo2b, fods, N);
    k_p2<<<pgrid, TPB, 0, stream>>>(rowptr, ecol, dis, fo2b, fods, tptr, dptr,
                                    delta, N);
    k_final<<<NFB, TPB, 0, stream>>>(xr, xi, delta, out, N, interleaved, partials2);
    k_sum<<<1, TPB, 0, stream>>>(partials2, NFB, S);
    k_norm<<<(N + TPB - 1) / TPB, TPB, 0, stream>>>(out, N, S);
}